// Round 1
// baseline (1736.938 us; speedup 1.0000x reference)
//
#include <hip/hip_runtime.h>
#include <math.h>

#define T_ 80
#define B_ 32
#define N_ 2560            // T_*B_
#define LH_ 256

__device__ __forceinline__ float lrelu(float v) { return v > 0.f ? v : 0.01f * v; }

// ---------- small weight-layout kernels ----------
__global__ void transpose_k(const float* __restrict__ src, float* __restrict__ dst,
                            int rows, int cols) {
    int gid = blockIdx.x * 256 + threadIdx.x;
    if (gid >= rows * cols) return;
    int r = gid / cols, c = gid % cols;
    dst[c * rows + r] = src[gid];
}

__global__ void pack_whh_k(const float* __restrict__ whh, float* __restrict__ whhP) {
    int gid = blockIdx.x * 256 + threadIdx.x;   // 1024*256
    if (gid >= 1024 * 256) return;
    int j = gid / 256, k = gid % 256;
    whhP[((k >> 2) * 1024 + j) * 4 + (k & 3)] = whh[gid];
}

// ---------- conv1: [N,4,84,84] -> [N,32,20,20], k=8 s=4 p=1 ----------
__global__ __launch_bounds__(256) void conv1_k(
    const float* __restrict__ x, const float* __restrict__ wT,   // wT[256][32]
    const float* __restrict__ bias, float* __restrict__ out) {
    int gid = blockIdx.x * 256 + threadIdx.x;       // N_*400
    int n = gid / 400, p = gid % 400;
    int oy = p / 20, ox = p % 20;
    const float* xp = x + (size_t)n * 4 * 84 * 84;
    int iy0 = oy * 4 - 1, ix0 = ox * 4 - 1;
    float acc[32];
#pragma unroll
    for (int oc = 0; oc < 32; ++oc) acc[oc] = 0.f;
    for (int ci = 0; ci < 4; ++ci) {
        const float* xc = xp + ci * 84 * 84;
#pragma unroll
        for (int ky = 0; ky < 8; ++ky) {
            int y = iy0 + ky;
            if (y < 0) continue;                     // only oy==0,ky==0; no upper OOB
            const float* xr = xc + y * 84;
            const float* wr = wT + (ci * 64 + ky * 8) * 32;
#pragma unroll
            for (int kx = 0; kx < 8; ++kx) {
                int xx = ix0 + kx;
                if (xx < 0) continue;                // only ox==0,kx==0
                float xin = xr[xx];
                const float* wv = wr + kx * 32;
#pragma unroll
                for (int oc = 0; oc < 32; ++oc)
                    acc[oc] = fmaf(xin, wv[oc], acc[oc]);
            }
        }
    }
    float* op = out + (size_t)n * 12800 + p;
#pragma unroll
    for (int oc = 0; oc < 32; ++oc)
        op[oc * 400] = lrelu(acc[oc] + bias[oc]);
}

// ---------- conv2: [N,32,20,20] -> [N,64,9,9], k=4 s=2 ----------
__global__ __launch_bounds__(256) void conv2_k(
    const float* __restrict__ in, const float* __restrict__ wT,  // wT[512][64]
    const float* __restrict__ bias, float* __restrict__ out) {
    int gid = blockIdx.x * 256 + threadIdx.x;       // N_*81
    if (gid >= N_ * 81) return;
    int n = gid / 81, p = gid % 81;
    int oy = p / 9, ox = p % 9;
    const float* xp = in + (size_t)n * 12800 + (oy * 2) * 20 + ox * 2;
    float acc[64];
#pragma unroll
    for (int oc = 0; oc < 64; ++oc) acc[oc] = 0.f;
    for (int ci = 0; ci < 32; ++ci) {
        const float* xc = xp + ci * 400;
        float xin[16];
#pragma unroll
        for (int ky = 0; ky < 4; ++ky)
#pragma unroll
            for (int kx = 0; kx < 4; ++kx)
                xin[ky * 4 + kx] = xc[ky * 20 + kx];
        const float* wr = wT + ci * 16 * 64;
#pragma unroll
        for (int q = 0; q < 16; ++q) {
            float xv = xin[q];
            const float* wv = wr + q * 64;
#pragma unroll
            for (int oc = 0; oc < 64; ++oc)
                acc[oc] = fmaf(xv, wv[oc], acc[oc]);
        }
    }
    float* op = out + (size_t)n * 5184 + p;
#pragma unroll
    for (int oc = 0; oc < 64; ++oc)
        op[oc * 81] = lrelu(acc[oc] + bias[oc]);
}

// ---------- conv3: [N,64,9,9] -> [N,64,7,7] -> flat h3[N][3136] ----------
__global__ __launch_bounds__(256) void conv3_k(
    const float* __restrict__ in, const float* __restrict__ wT,  // wT[576][64]
    const float* __restrict__ bias, float* __restrict__ out) {
    int gid = blockIdx.x * 256 + threadIdx.x;       // N_*49
    if (gid >= N_ * 49) return;
    int n = gid / 49, p = gid % 49;
    int oy = p / 7, ox = p % 7;
    const float* xp = in + (size_t)n * 5184 + oy * 9 + ox;
    float acc[64];
#pragma unroll
    for (int oc = 0; oc < 64; ++oc) acc[oc] = 0.f;
    for (int ci = 0; ci < 64; ++ci) {
        const float* xc = xp + ci * 81;
        float xin[9];
#pragma unroll
        for (int ky = 0; ky < 3; ++ky)
#pragma unroll
            for (int kx = 0; kx < 3; ++kx)
                xin[ky * 3 + kx] = xc[ky * 9 + kx];
        const float* wr = wT + ci * 9 * 64;
#pragma unroll
        for (int q = 0; q < 9; ++q) {
            float xv = xin[q];
            const float* wv = wr + q * 64;
#pragma unroll
            for (int oc = 0; oc < 64; ++oc)
                acc[oc] = fmaf(xv, wv[oc], acc[oc]);
        }
    }
    float* op = out + (size_t)n * 3136 + p;          // [n][oc*49+p]
#pragma unroll
    for (int oc = 0; oc < 64; ++oc)
        op[oc * 49] = lrelu(acc[oc] + bias[oc]);
}

// ---------- generic C[M,N] = A[M,K] * B[N,K]^T (+bias, +lrelu) ----------
template <int ACT>
__global__ __launch_bounds__(256) void gemm_tn(
    const float* __restrict__ A, int lda,
    const float* __restrict__ B, int ldb,
    const float* __restrict__ bias,
    float* __restrict__ C, int ldc, int K) {
    __shared__ __align__(16) float As[8][64];
    __shared__ __align__(16) float Bs[8][64];
    int m0 = blockIdx.y * 64, n0 = blockIdx.x * 64;
    int tid = threadIdx.x;
    int tx = tid & 15, ty = tid >> 4;
    float acc[4][4];
#pragma unroll
    for (int i = 0; i < 4; ++i)
#pragma unroll
        for (int j = 0; j < 4; ++j) acc[i][j] = 0.f;

    for (int k0 = 0; k0 < K; k0 += 8) {
#pragma unroll
        for (int l = 0; l < 2; ++l) {
            int e = tid + l * 256;
            int row = e >> 3, kk = e & 7;
            As[kk][row] = A[(size_t)(m0 + row) * lda + k0 + kk];
            Bs[kk][row] = B[(size_t)(n0 + row) * ldb + k0 + kk];
        }
        __syncthreads();
#pragma unroll
        for (int kk = 0; kk < 8; ++kk) {
            float4 av = *(const float4*)&As[kk][ty * 4];
            float4 bv = *(const float4*)&Bs[kk][tx * 4];
            float a[4] = {av.x, av.y, av.z, av.w};
            float b[4] = {bv.x, bv.y, bv.z, bv.w};
#pragma unroll
            for (int i = 0; i < 4; ++i)
#pragma unroll
                for (int j = 0; j < 4; ++j)
                    acc[i][j] = fmaf(a[i], b[j], acc[i][j]);
        }
        __syncthreads();
    }
#pragma unroll
    for (int i = 0; i < 4; ++i) {
        int row = m0 + ty * 4 + i;
#pragma unroll
        for (int j = 0; j < 4; ++j) {
            int col = n0 + tx * 4 + j;
            float v = acc[i][j];
            if (bias) v += bias[col];
            if (ACT == 1) v = lrelu(v);
            C[(size_t)row * ldc + col] = v;
        }
    }
}

// ---------- gates epilogue: + bih + bhh + reward*wih[:,512] + wih[:,513+la] ----------
__global__ void gx_epi_k(float* __restrict__ gx, const float* __restrict__ reward,
                         const int* __restrict__ la, const float* __restrict__ wih,
                         const float* __restrict__ bih, const float* __restrict__ bhh) {
    int gid = blockIdx.x * 256 + threadIdx.x;       // N_*1024
    int n = gid >> 10, j = gid & 1023;
    const float* wr = wih + (size_t)j * 529;
    gx[gid] += bih[j] + bhh[j] + reward[n] * wr[512] + wr[513 + la[n]];
}

// ---------- LSTM: one workgroup per batch element ----------
__global__ __launch_bounds__(1024) void lstm_k(
    const float* __restrict__ gx,        // [N_,1024]
    const float* __restrict__ whhP,      // packed [(256/4)][1024][4]
    const unsigned char* __restrict__ dones,
    const float* __restrict__ hx,        // [2,B_,256]
    float* __restrict__ hs) {            // [N_,256]
    int b = blockIdx.x, tid = threadIdx.x;
    __shared__ __align__(16) float hh_s[256];
    __shared__ float cc_s[256];
    __shared__ float gate_s[1024];
    if (tid < 256) {
        hh_s[tid] = hx[b * LH_ + tid];
        cc_s[tid] = hx[B_ * LH_ + b * LH_ + tid];
    }
    __syncthreads();
    const float4* wp = (const float4*)whhP + tid;
    for (int t = 0; t < T_; ++t) {
        int nb = t * B_ + b;
        bool dn = dones[nb] != 0;
        float acc = gx[(size_t)nb * 1024 + tid];
        if (!dn) {
#pragma unroll 8
            for (int k4 = 0; k4 < 64; ++k4) {
                float4 w4 = wp[k4 * 1024];
                float4 h4 = *(const float4*)&hh_s[k4 * 4];
                acc = fmaf(w4.x, h4.x, acc);
                acc = fmaf(w4.y, h4.y, acc);
                acc = fmaf(w4.z, h4.z, acc);
                acc = fmaf(w4.w, h4.w, acc);
            }
        }
        gate_s[tid] = acc;
        __syncthreads();
        if (tid < 256) {
            float gi = gate_s[tid], gf = gate_s[256 + tid];
            float gg = gate_s[512 + tid], go = gate_s[768 + tid];
            float ccv = dn ? 0.f : cc_s[tid];
            float si = 1.f / (1.f + expf(-gi));
            float sf = 1.f / (1.f + expf(-gf));
            float so = 1.f / (1.f + expf(-go));
            float c2 = sf * ccv + si * tanhf(gg);
            float h2 = so * tanhf(c2);
            cc_s[tid] = c2;
            hh_s[tid] = h2;
            hs[(size_t)nb * LH_ + tid] = h2;
        }
        __syncthreads();
    }
}

// ---------- heads: logits[N,16] + NaN guard, values[N] ----------
__global__ void head_k(const float* __restrict__ hs,
                       const float* __restrict__ aw, const float* __restrict__ ab,
                       const float* __restrict__ cw, const float* __restrict__ cb,
                       float* __restrict__ out) {
    int gid = blockIdx.x * 256 + threadIdx.x;       // N_*17
    if (gid >= N_ * 17) return;
    int n = gid / 17, r = gid % 17;
    const float* f = hs + (size_t)n * 256;
    if (r < 16) {
        const float* w = aw + r * 256;
        float acc = ab[r];
        for (int k = 0; k < 256; ++k) acc = fmaf(f[k], w[k], acc);
        if (isnan(acc)) acc = 1e-12f;
        out[(size_t)n * 16 + r] = acc;
    } else {
        float acc = cb[0];
        for (int k = 0; k < 256; ++k) acc = fmaf(f[k], cw[k], acc);
        out[(size_t)N_ * 16 + n] = acc;
    }
}

extern "C" void kernel_launch(void* const* d_in, const int* in_sizes, int n_in,
                              void* d_out, int out_size, void* d_ws, size_t ws_size,
                              hipStream_t stream) {
    const float* x      = (const float*)d_in[0];
    const int* la       = (const int*)d_in[1];
    const float* reward = (const float*)d_in[2];
    const unsigned char* dones = (const unsigned char*)d_in[3];
    const float* hx     = (const float*)d_in[4];
    const float* c1w = (const float*)d_in[5];  const float* c1b = (const float*)d_in[6];
    const float* c2w = (const float*)d_in[7];  const float* c2b = (const float*)d_in[8];
    const float* c3w = (const float*)d_in[9];  const float* c3b = (const float*)d_in[10];
    const float* fcw = (const float*)d_in[11]; const float* fcb = (const float*)d_in[12];
    const float* wih = (const float*)d_in[13]; const float* whh = (const float*)d_in[14];
    const float* bih = (const float*)d_in[15]; const float* bhh = (const float*)d_in[16];
    const float* aw  = (const float*)d_in[17]; const float* ab  = (const float*)d_in[18];
    const float* cw  = (const float*)d_in[19]; const float* cb  = (const float*)d_in[20];

    float* ws = (float*)d_ws;
    // region A (reused): h1 [N,32,20,20] then h3/hfc/gx
    float* h1  = ws;                          // 32,768,000 f
    float* h3  = ws;                          //  8,028,160 f
    float* hfc = ws + 8028160;                //  1,310,720 f
    float* gx  = ws + 9338880;                //  2,621,440 f
    // region B (reused): h2 [N,64,9,9] then hs
    float* h2  = ws + 32768000;               // 13,271,040 f
    float* hs  = ws + 32768000;               //    655,360 f
    // region C: persistent packed weights
    float* whhP = ws + 46039040;              //   262,144 f
    float* wT1  = whhP + 262144;              //     8,192 f
    float* wT2  = wT1 + 8192;                 //    32,768 f
    float* wT3  = wT2 + 32768;                //    36,864 f

    transpose_k<<<32, 256, 0, stream>>>(c1w, wT1, 32, 256);
    transpose_k<<<128, 256, 0, stream>>>(c2w, wT2, 64, 512);
    transpose_k<<<144, 256, 0, stream>>>(c3w, wT3, 64, 576);
    pack_whh_k<<<1024, 256, 0, stream>>>(whh, whhP);

    conv1_k<<<4000, 256, 0, stream>>>(x, wT1, c1b, h1);
    conv2_k<<<810, 256, 0, stream>>>(h1, wT2, c2b, h2);
    conv3_k<<<490, 256, 0, stream>>>(h2, wT3, c3b, h3);

    gemm_tn<1><<<dim3(8, 40), 256, 0, stream>>>(h3, 3136, fcw, 3136, fcb, hfc, 512, 3136);
    gemm_tn<0><<<dim3(16, 40), 256, 0, stream>>>(hfc, 512, wih, 529, nullptr, gx, 1024, 512);
    gx_epi_k<<<10240, 256, 0, stream>>>(gx, reward, la, wih, bih, bhh);

    lstm_k<<<32, 1024, 0, stream>>>(gx, whhP, dones, hx, hs);
    head_k<<<170, 256, 0, stream>>>(hs, aw, ab, cw, cb, (float*)d_out);
}

// Round 2
// 1575.219 us; speedup vs baseline: 1.1027x; 1.1027x over previous
//
#include <hip/hip_runtime.h>
#include <math.h>

#define T_ 80
#define B_ 32
#define N_ 2560            // T_*B_
#define LH_ 256

__device__ __forceinline__ float lrelu(float v) { return v > 0.f ? v : 0.01f * v; }

// ---------- small weight-layout kernels ----------
__global__ void transpose_k(const float* __restrict__ src, float* __restrict__ dst,
                            int rows, int cols) {
    int gid = blockIdx.x * 256 + threadIdx.x;
    if (gid >= rows * cols) return;
    int r = gid / cols, c = gid % cols;
    dst[c * rows + r] = src[gid];
}

__global__ void zero_flags_k(int* __restrict__ flags) {
    flags[threadIdx.x] = 0;
}

// ---------- conv1: [N,4,84,84] -> [N,32,20,20], k=8 s=4 p=1 ----------
__global__ __launch_bounds__(256) void conv1_k(
    const float* __restrict__ x, const float* __restrict__ wT,   // wT[256][32]
    const float* __restrict__ bias, float* __restrict__ out) {
    int gid = blockIdx.x * 256 + threadIdx.x;       // N_*400
    int n = gid / 400, p = gid % 400;
    int oy = p / 20, ox = p % 20;
    const float* xp = x + (size_t)n * 4 * 84 * 84;
    int iy0 = oy * 4 - 1, ix0 = ox * 4 - 1;
    float acc[32];
#pragma unroll
    for (int oc = 0; oc < 32; ++oc) acc[oc] = 0.f;
    for (int ci = 0; ci < 4; ++ci) {
        const float* xc = xp + ci * 84 * 84;
#pragma unroll
        for (int ky = 0; ky < 8; ++ky) {
            int y = iy0 + ky;
            if (y < 0) continue;                     // only oy==0,ky==0; no upper OOB
            const float* xr = xc + y * 84;
            const float* wr = wT + (ci * 64 + ky * 8) * 32;
#pragma unroll
            for (int kx = 0; kx < 8; ++kx) {
                int xx = ix0 + kx;
                if (xx < 0) continue;                // only ox==0,kx==0
                float xin = xr[xx];
                const float* wv = wr + kx * 32;
#pragma unroll
                for (int oc = 0; oc < 32; ++oc)
                    acc[oc] = fmaf(xin, wv[oc], acc[oc]);
            }
        }
    }
    float* op = out + (size_t)n * 12800 + p;
#pragma unroll
    for (int oc = 0; oc < 32; ++oc)
        op[oc * 400] = lrelu(acc[oc] + bias[oc]);
}

// ---------- conv2: [N,32,20,20] -> [N,64,9,9], k=4 s=2 ----------
__global__ __launch_bounds__(256) void conv2_k(
    const float* __restrict__ in, const float* __restrict__ wT,  // wT[512][64]
    const float* __restrict__ bias, float* __restrict__ out) {
    int gid = blockIdx.x * 256 + threadIdx.x;       // N_*81
    if (gid >= N_ * 81) return;
    int n = gid / 81, p = gid % 81;
    int oy = p / 9, ox = p % 9;
    const float* xp = in + (size_t)n * 12800 + (oy * 2) * 20 + ox * 2;
    float acc[64];
#pragma unroll
    for (int oc = 0; oc < 64; ++oc) acc[oc] = 0.f;
    for (int ci = 0; ci < 32; ++ci) {
        const float* xc = xp + ci * 400;
        float xin[16];
#pragma unroll
        for (int ky = 0; ky < 4; ++ky)
#pragma unroll
            for (int kx = 0; kx < 4; ++kx)
                xin[ky * 4 + kx] = xc[ky * 20 + kx];
        const float* wr = wT + ci * 16 * 64;
#pragma unroll
        for (int q = 0; q < 16; ++q) {
            float xv = xin[q];
            const float* wv = wr + q * 64;
#pragma unroll
            for (int oc = 0; oc < 64; ++oc)
                acc[oc] = fmaf(xv, wv[oc], acc[oc]);
        }
    }
    float* op = out + (size_t)n * 5184 + p;
#pragma unroll
    for (int oc = 0; oc < 64; ++oc)
        op[oc * 81] = lrelu(acc[oc] + bias[oc]);
}

// ---------- conv3: [N,64,9,9] -> [N,64,7,7] -> flat h3[N][3136] ----------
__global__ __launch_bounds__(256) void conv3_k(
    const float* __restrict__ in, const float* __restrict__ wT,  // wT[576][64]
    const float* __restrict__ bias, float* __restrict__ out) {
    int gid = blockIdx.x * 256 + threadIdx.x;       // N_*49
    if (gid >= N_ * 49) return;
    int n = gid / 49, p = gid % 49;
    int oy = p / 7, ox = p % 7;
    const float* xp = in + (size_t)n * 5184 + oy * 9 + ox;
    float acc[64];
#pragma unroll
    for (int oc = 0; oc < 64; ++oc) acc[oc] = 0.f;
    for (int ci = 0; ci < 64; ++ci) {
        const float* xc = xp + ci * 81;
        float xin[9];
#pragma unroll
        for (int ky = 0; ky < 3; ++ky)
#pragma unroll
            for (int kx = 0; kx < 3; ++kx)
                xin[ky * 3 + kx] = xc[ky * 9 + kx];
        const float* wr = wT + ci * 9 * 64;
#pragma unroll
        for (int q = 0; q < 9; ++q) {
            float xv = xin[q];
            const float* wv = wr + q * 64;
#pragma unroll
            for (int oc = 0; oc < 64; ++oc)
                acc[oc] = fmaf(xv, wv[oc], acc[oc]);
        }
    }
    float* op = out + (size_t)n * 3136 + p;          // [n][oc*49+p]
#pragma unroll
    for (int oc = 0; oc < 64; ++oc)
        op[oc * 49] = lrelu(acc[oc] + bias[oc]);
}

// ---------- generic C[M,N] = A[M,K] * B[N,K]^T (+bias, +lrelu) ----------
template <int ACT>
__global__ __launch_bounds__(256) void gemm_tn(
    const float* __restrict__ A, int lda,
    const float* __restrict__ B, int ldb,
    const float* __restrict__ bias,
    float* __restrict__ C, int ldc, int K) {
    __shared__ __align__(16) float As[8][64];
    __shared__ __align__(16) float Bs[8][64];
    int m0 = blockIdx.y * 64, n0 = blockIdx.x * 64;
    int tid = threadIdx.x;
    int tx = tid & 15, ty = tid >> 4;
    float acc[4][4];
#pragma unroll
    for (int i = 0; i < 4; ++i)
#pragma unroll
        for (int j = 0; j < 4; ++j) acc[i][j] = 0.f;

    for (int k0 = 0; k0 < K; k0 += 8) {
#pragma unroll
        for (int l = 0; l < 2; ++l) {
            int e = tid + l * 256;
            int row = e >> 3, kk = e & 7;
            As[kk][row] = A[(size_t)(m0 + row) * lda + k0 + kk];
            Bs[kk][row] = B[(size_t)(n0 + row) * ldb + k0 + kk];
        }
        __syncthreads();
#pragma unroll
        for (int kk = 0; kk < 8; ++kk) {
            float4 av = *(const float4*)&As[kk][ty * 4];
            float4 bv = *(const float4*)&Bs[kk][tx * 4];
            float a[4] = {av.x, av.y, av.z, av.w};
            float b[4] = {bv.x, bv.y, bv.z, bv.w};
#pragma unroll
            for (int i = 0; i < 4; ++i)
#pragma unroll
                for (int j = 0; j < 4; ++j)
                    acc[i][j] = fmaf(a[i], b[j], acc[i][j]);
        }
        __syncthreads();
    }
#pragma unroll
    for (int i = 0; i < 4; ++i) {
        int row = m0 + ty * 4 + i;
#pragma unroll
        for (int j = 0; j < 4; ++j) {
            int col = n0 + tx * 4 + j;
            float v = acc[i][j];
            if (bias) v += bias[col];
            if (ACT == 1) v = lrelu(v);
            C[(size_t)row * ldc + col] = v;
        }
    }
}

// ---------- gates epilogue: + bih + bhh + reward*wih[:,512] + wih[:,513+la] ----------
__global__ void gx_epi_k(float* __restrict__ gx, const float* __restrict__ reward,
                         const int* __restrict__ la, const float* __restrict__ wih,
                         const float* __restrict__ bih, const float* __restrict__ bhh) {
    int gid = blockIdx.x * 256 + threadIdx.x;       // N_*1024
    int n = gid >> 10, j = gid & 1023;
    const float* wr = wih + (size_t)j * 529;
    gx[gid] += bih[j] + bhh[j] + reward[n] * wr[512] + wr[513 + la[n]];
}

// ---------- LSTM v2: 256 WGs = 8 hidden-slices x 32 batches ----------
// Each WG owns 32 hidden units (128 gate rows). Whh slice lives in VGPRs:
// thread (r,q) holds Whh[grow(r)][q*64 .. q*64+63] in 16 float4 regs.
// Per step, the 8 WGs of a batch exchange their 32-float h-slices through a
// global ping-pong buffer guarded by per-WG step flags (agent-scope atomics).
// Grid=256 blocks, 8 waves, ~<128 VGPR -> all blocks co-resident.
__global__ __launch_bounds__(512, 2) void lstm256_k(
    const float* __restrict__ gx,        // [N_,1024]
    const float* __restrict__ whh,       // [1024,256]
    const unsigned char* __restrict__ dones,
    const float* __restrict__ hx,        // [2,B_,256]
    float* __restrict__ hs,              // [N_,256]
    float* __restrict__ hbuf,            // [2][B_][256] ping-pong h exchange
    int* __restrict__ flags) {           // [B_*8] last completed step per WG
    const int tid = threadIdx.x;
    const int b = blockIdx.x & 31;       // batch
    const int s = blockIdx.x >> 5;       // hidden slice 0..7 (same (idx%8) group -> same XCD)
    const int r = tid >> 2;              // local gate row 0..127
    const int q = tid & 3;               // k-quarter
    const int g = r >> 5, j = r & 31;
    const int grow = g * 256 + s * 32 + j;   // global gate row

    __shared__ __align__(16) float h_lds[256];
    __shared__ float gate_s[128];

    // ---- load Whh slice into registers (once) ----
    float4 wreg[16];
    {
        const float4* wrow = (const float4*)(whh + (size_t)grow * 256 + q * 64);
#pragma unroll
        for (int c = 0; c < 16; ++c) wreg[c] = wrow[c];
    }

    // ---- carry c for this WG's hidden units (tid<32 owns one each) ----
    float cc = 0.f;
    if (tid < 32) cc = hx[(size_t)B_ * LH_ + b * LH_ + s * 32 + tid];

    for (int t = 1; t <= T_; ++t) {
        const int nb = (t - 1) * B_ + b;
        const bool dn = dones[nb] != 0;
        float gxv = 0.f;
        if (q == 0) gxv = gx[(size_t)nb * 1024 + grow];   // issue early, indep of h

        // ---- wait for previous step's h slices ----
        if (t > 1) {
            if (tid < 8) {
                while (__hip_atomic_load(&flags[b * 8 + tid], __ATOMIC_ACQUIRE,
                                         __HIP_MEMORY_SCOPE_AGENT) < t - 1)
                    __builtin_amdgcn_s_sleep(1);
            }
            __syncthreads();
        }
        // ---- stage full h into LDS ----
        if (tid < 256) {
            float hv;
            if (t == 1) hv = hx[b * LH_ + tid];
            else        hv = __hip_atomic_load(&hbuf[((t - 1) & 1) * B_ * LH_ + b * LH_ + tid],
                                               __ATOMIC_RELAXED, __HIP_MEMORY_SCOPE_AGENT);
            h_lds[tid] = dn ? 0.f : hv;
        }
        __syncthreads();

        // ---- matvec: 128 rows x 256 k, 4 threads per row ----
        float acc = 0.f;
        const float4* h4 = (const float4*)h_lds + q * 16;
#pragma unroll
        for (int c = 0; c < 16; ++c) {
            float4 hv = h4[c];
            acc = fmaf(wreg[c].x, hv.x, acc);
            acc = fmaf(wreg[c].y, hv.y, acc);
            acc = fmaf(wreg[c].z, hv.z, acc);
            acc = fmaf(wreg[c].w, hv.w, acc);
        }
        acc += __shfl_xor(acc, 1);
        acc += __shfl_xor(acc, 2);
        if (q == 0) gate_s[r] = acc + gxv;
        __syncthreads();

        // ---- pointwise cell (wave 0, lanes 0..31) + publish ----
        if (tid < 32) {
            float gi = gate_s[tid], gf = gate_s[32 + tid];
            float gg = gate_s[64 + tid], go = gate_s[96 + tid];
            float ccv = dn ? 0.f : cc;
            float si = 1.f / (1.f + expf(-gi));
            float sf = 1.f / (1.f + expf(-gf));
            float so = 1.f / (1.f + expf(-go));
            float c2 = sf * ccv + si * tanhf(gg);
            float h2 = so * tanhf(c2);
            cc = c2;
            int hidx = s * 32 + tid;
            hs[(size_t)nb * LH_ + hidx] = h2;
            __hip_atomic_store(&hbuf[(t & 1) * B_ * LH_ + b * LH_ + hidx], h2,
                               __ATOMIC_RELAXED, __HIP_MEMORY_SCOPE_AGENT);
        }
        if (tid == 0)   // same wave as the h stores -> release orders them
            __hip_atomic_store(&flags[b * 8 + s], t, __ATOMIC_RELEASE,
                               __HIP_MEMORY_SCOPE_AGENT);
        // next iteration's barriers protect h_lds/gate_s reuse
    }
}

// ---------- heads: logits[N,16] + NaN guard, values[N] ----------
__global__ void head_k(const float* __restrict__ hs,
                       const float* __restrict__ aw, const float* __restrict__ ab,
                       const float* __restrict__ cw, const float* __restrict__ cb,
                       float* __restrict__ out) {
    int gid = blockIdx.x * 256 + threadIdx.x;       // N_*17
    if (gid >= N_ * 17) return;
    int n = gid / 17, r = gid % 17;
    const float* f = hs + (size_t)n * 256;
    if (r < 16) {
        const float* w = aw + r * 256;
        float acc = ab[r];
        for (int k = 0; k < 256; ++k) acc = fmaf(f[k], w[k], acc);
        if (isnan(acc)) acc = 1e-12f;
        out[(size_t)n * 16 + r] = acc;
    } else {
        float acc = cb[0];
        for (int k = 0; k < 256; ++k) acc = fmaf(f[k], cw[k], acc);
        out[(size_t)N_ * 16 + n] = acc;
    }
}

extern "C" void kernel_launch(void* const* d_in, const int* in_sizes, int n_in,
                              void* d_out, int out_size, void* d_ws, size_t ws_size,
                              hipStream_t stream) {
    const float* x      = (const float*)d_in[0];
    const int* la       = (const int*)d_in[1];
    const float* reward = (const float*)d_in[2];
    const unsigned char* dones = (const unsigned char*)d_in[3];
    const float* hx     = (const float*)d_in[4];
    const float* c1w = (const float*)d_in[5];  const float* c1b = (const float*)d_in[6];
    const float* c2w = (const float*)d_in[7];  const float* c2b = (const float*)d_in[8];
    const float* c3w = (const float*)d_in[9];  const float* c3b = (const float*)d_in[10];
    const float* fcw = (const float*)d_in[11]; const float* fcb = (const float*)d_in[12];
    const float* wih = (const float*)d_in[13]; const float* whh = (const float*)d_in[14];
    const float* bih = (const float*)d_in[15]; const float* bhh = (const float*)d_in[16];
    const float* aw  = (const float*)d_in[17]; const float* ab  = (const float*)d_in[18];
    const float* cw  = (const float*)d_in[19]; const float* cb  = (const float*)d_in[20];

    float* ws = (float*)d_ws;
    // region A (reused): h1 [N,32,20,20] then h3/hfc/gx
    float* h1  = ws;                          // 32,768,000 f
    float* h3  = ws;                          //  8,028,160 f
    float* hfc = ws + 8028160;                //  1,310,720 f
    float* gx  = ws + 9338880;                //  2,621,440 f
    // region B (reused): h2 [N,64,9,9] then hs
    float* h2  = ws + 32768000;               // 13,271,040 f
    float* hs  = ws + 32768000;               //    655,360 f
    // region C: persistent small buffers
    float* hbuf = ws + 46039040;              //    16,384 f
    int*   flags = (int*)(ws + 46055424);     //       256 i
    float* wT1  = ws + 46055680;              //     8,192 f
    float* wT2  = wT1 + 8192;                 //    32,768 f
    float* wT3  = wT2 + 32768;                //    36,864 f

    transpose_k<<<32, 256, 0, stream>>>(c1w, wT1, 32, 256);
    transpose_k<<<128, 256, 0, stream>>>(c2w, wT2, 64, 512);
    transpose_k<<<144, 256, 0, stream>>>(c3w, wT3, 64, 576);
    zero_flags_k<<<1, 256, 0, stream>>>(flags);

    conv1_k<<<4000, 256, 0, stream>>>(x, wT1, c1b, h1);
    conv2_k<<<810, 256, 0, stream>>>(h1, wT2, c2b, h2);
    conv3_k<<<490, 256, 0, stream>>>(h2, wT3, c3b, h3);

    gemm_tn<1><<<dim3(8, 40), 256, 0, stream>>>(h3, 3136, fcw, 3136, fcb, hfc, 512, 3136);
    gemm_tn<0><<<dim3(16, 40), 256, 0, stream>>>(hfc, 512, wih, 529, nullptr, gx, 1024, 512);
    gx_epi_k<<<10240, 256, 0, stream>>>(gx, reward, la, wih, bih, bhh);

    lstm256_k<<<256, 512, 0, stream>>>(gx, whh, dones, hx, hs, hbuf, flags);
    head_k<<<170, 256, 0, stream>>>(hs, aw, ab, cw, cb, (float*)d_out);
}

// Round 3
// 1495.649 us; speedup vs baseline: 1.1613x; 1.0532x over previous
//
#include <hip/hip_runtime.h>
#include <math.h>

#define T_ 80
#define B_ 32
#define N_ 2560            // T_*B_
#define LH_ 256

__device__ __forceinline__ float lrelu(float v) { return v > 0.f ? v : 0.01f * v; }

// ---------- small weight-layout kernels ----------
__global__ void transpose_k(const float* __restrict__ src, float* __restrict__ dst,
                            int rows, int cols) {
    int gid = blockIdx.x * 256 + threadIdx.x;
    if (gid >= rows * cols) return;
    int r = gid / cols, c = gid % cols;
    dst[c * rows + r] = src[gid];
}

__global__ void zero_flags_k(int* __restrict__ flags) {
    flags[threadIdx.x] = 0;
}

// ---------- conv1: [N,4,84,84] -> [N,32,20,20], k=8 s=4 p=1 ----------
__global__ __launch_bounds__(256) void conv1_k(
    const float* __restrict__ x, const float* __restrict__ wT,   // wT[256][32]
    const float* __restrict__ bias, float* __restrict__ out) {
    int gid = blockIdx.x * 256 + threadIdx.x;       // N_*400
    int n = gid / 400, p = gid % 400;
    int oy = p / 20, ox = p % 20;
    const float* xp = x + (size_t)n * 4 * 84 * 84;
    int iy0 = oy * 4 - 1, ix0 = ox * 4 - 1;
    float acc[32];
#pragma unroll
    for (int oc = 0; oc < 32; ++oc) acc[oc] = 0.f;
    for (int ci = 0; ci < 4; ++ci) {
        const float* xc = xp + ci * 84 * 84;
#pragma unroll
        for (int ky = 0; ky < 8; ++ky) {
            int y = iy0 + ky;
            if (y < 0) continue;                     // only oy==0,ky==0; no upper OOB
            const float* xr = xc + y * 84;
            const float* wr = wT + (ci * 64 + ky * 8) * 32;
#pragma unroll
            for (int kx = 0; kx < 8; ++kx) {
                int xx = ix0 + kx;
                if (xx < 0) continue;                // only ox==0,kx==0
                float xin = xr[xx];
                const float* wv = wr + kx * 32;
#pragma unroll
                for (int oc = 0; oc < 32; ++oc)
                    acc[oc] = fmaf(xin, wv[oc], acc[oc]);
            }
        }
    }
    float* op = out + (size_t)n * 12800 + p;
#pragma unroll
    for (int oc = 0; oc < 32; ++oc)
        op[oc * 400] = lrelu(acc[oc] + bias[oc]);
}

// ---------- conv2: [N,32,20,20] -> [N,64,9,9], k=4 s=2 ----------
__global__ __launch_bounds__(256) void conv2_k(
    const float* __restrict__ in, const float* __restrict__ wT,  // wT[512][64]
    const float* __restrict__ bias, float* __restrict__ out) {
    int gid = blockIdx.x * 256 + threadIdx.x;       // N_*81
    if (gid >= N_ * 81) return;
    int n = gid / 81, p = gid % 81;
    int oy = p / 9, ox = p % 9;
    const float* xp = in + (size_t)n * 12800 + (oy * 2) * 20 + ox * 2;
    float acc[64];
#pragma unroll
    for (int oc = 0; oc < 64; ++oc) acc[oc] = 0.f;
    for (int ci = 0; ci < 32; ++ci) {
        const float* xc = xp + ci * 400;
        float xin[16];
#pragma unroll
        for (int ky = 0; ky < 4; ++ky)
#pragma unroll
            for (int kx = 0; kx < 4; ++kx)
                xin[ky * 4 + kx] = xc[ky * 20 + kx];
        const float* wr = wT + ci * 16 * 64;
#pragma unroll
        for (int q = 0; q < 16; ++q) {
            float xv = xin[q];
            const float* wv = wr + q * 64;
#pragma unroll
            for (int oc = 0; oc < 64; ++oc)
                acc[oc] = fmaf(xv, wv[oc], acc[oc]);
        }
    }
    float* op = out + (size_t)n * 5184 + p;
#pragma unroll
    for (int oc = 0; oc < 64; ++oc)
        op[oc * 81] = lrelu(acc[oc] + bias[oc]);
}

// ---------- conv3: [N,64,9,9] -> [N,64,7,7] -> flat h3[N][3136] ----------
__global__ __launch_bounds__(256) void conv3_k(
    const float* __restrict__ in, const float* __restrict__ wT,  // wT[576][64]
    const float* __restrict__ bias, float* __restrict__ out) {
    int gid = blockIdx.x * 256 + threadIdx.x;       // N_*49
    if (gid >= N_ * 49) return;
    int n = gid / 49, p = gid % 49;
    int oy = p / 7, ox = p % 7;
    const float* xp = in + (size_t)n * 5184 + oy * 9 + ox;
    float acc[64];
#pragma unroll
    for (int oc = 0; oc < 64; ++oc) acc[oc] = 0.f;
    for (int ci = 0; ci < 64; ++ci) {
        const float* xc = xp + ci * 81;
        float xin[9];
#pragma unroll
        for (int ky = 0; ky < 3; ++ky)
#pragma unroll
            for (int kx = 0; kx < 3; ++kx)
                xin[ky * 3 + kx] = xc[ky * 9 + kx];
        const float* wr = wT + ci * 9 * 64;
#pragma unroll
        for (int q = 0; q < 9; ++q) {
            float xv = xin[q];
            const float* wv = wr + q * 64;
#pragma unroll
            for (int oc = 0; oc < 64; ++oc)
                acc[oc] = fmaf(xv, wv[oc], acc[oc]);
        }
    }
    float* op = out + (size_t)n * 3136 + p;          // [n][oc*49+p]
#pragma unroll
    for (int oc = 0; oc < 64; ++oc)
        op[oc * 49] = lrelu(acc[oc] + bias[oc]);
}

// ---------- generic C[M,N] = A[M,K] * B[N,K]^T (+bias, +lrelu) ----------
template <int ACT>
__global__ __launch_bounds__(256) void gemm_tn(
    const float* __restrict__ A, int lda,
    const float* __restrict__ B, int ldb,
    const float* __restrict__ bias,
    float* __restrict__ C, int ldc, int K) {
    __shared__ __align__(16) float As[8][64];
    __shared__ __align__(16) float Bs[8][64];
    int m0 = blockIdx.y * 64, n0 = blockIdx.x * 64;
    int tid = threadIdx.x;
    int tx = tid & 15, ty = tid >> 4;
    float acc[4][4];
#pragma unroll
    for (int i = 0; i < 4; ++i)
#pragma unroll
        for (int j = 0; j < 4; ++j) acc[i][j] = 0.f;

    for (int k0 = 0; k0 < K; k0 += 8) {
#pragma unroll
        for (int l = 0; l < 2; ++l) {
            int e = tid + l * 256;
            int row = e >> 3, kk = e & 7;
            As[kk][row] = A[(size_t)(m0 + row) * lda + k0 + kk];
            Bs[kk][row] = B[(size_t)(n0 + row) * ldb + k0 + kk];
        }
        __syncthreads();
#pragma unroll
        for (int kk = 0; kk < 8; ++kk) {
            float4 av = *(const float4*)&As[kk][ty * 4];
            float4 bv = *(const float4*)&Bs[kk][tx * 4];
            float a[4] = {av.x, av.y, av.z, av.w};
            float b[4] = {bv.x, bv.y, bv.z, bv.w};
#pragma unroll
            for (int i = 0; i < 4; ++i)
#pragma unroll
                for (int j = 0; j < 4; ++j)
                    acc[i][j] = fmaf(a[i], b[j], acc[i][j]);
        }
        __syncthreads();
    }
#pragma unroll
    for (int i = 0; i < 4; ++i) {
        int row = m0 + ty * 4 + i;
#pragma unroll
        for (int j = 0; j < 4; ++j) {
            int col = n0 + tx * 4 + j;
            float v = acc[i][j];
            if (bias) v += bias[col];
            if (ACT == 1) v = lrelu(v);
            C[(size_t)row * ldc + col] = v;
        }
    }
}

// ---------- gates epilogue: + bih + bhh + reward*wih[:,512] + wih[:,513+la] ----------
__global__ void gx_epi_k(float* __restrict__ gx, const float* __restrict__ reward,
                         const int* __restrict__ la, const float* __restrict__ wih,
                         const float* __restrict__ bih, const float* __restrict__ bhh) {
    int gid = blockIdx.x * 256 + threadIdx.x;       // N_*1024
    int n = gid >> 10, j = gid & 1023;
    const float* wr = wih + (size_t)j * 529;
    gx[gid] += bih[j] + bhh[j] + reward[n] * wr[512] + wr[513 + la[n]];
}

// ---------- LSTM v3: 64 WGs = 8 hidden-slices x 8 batch-groups (4 batches each) ----
// Thread (r,q): r=tid>>2 in [0,128) gate row of this slice, q=tid&3 k-quarter.
// Weights w[grow][q*64..q*64+63] pinned in 16 float4 VGPRs via empty asm (prevents
// rematerialization: R2 showed VGPR=52 -> compiler re-loaded Whh from L2 every step).
// h staged in LDS with k-swizzled layout [bi][c][q][4] so the 4 q-lanes of a read
// hit distinct banks (R2: 3.1e7 bank conflicts from the q*64 stride).
// One flag per (group,slice) per step covers 4 batches -> 4x fewer sync round trips.
__global__ __launch_bounds__(512, 2) void lstm64_k(
    const float* __restrict__ gx,        // [N_,1024]
    const float* __restrict__ whh,       // [1024,256]
    const unsigned char* __restrict__ dones,
    const float* __restrict__ hx,        // [2,B_,256]
    float* __restrict__ hs,              // [N_,256]
    float* __restrict__ hbuf,            // [2][B_][256] ping-pong h exchange
    int* __restrict__ flags) {           // [8 groups][8 slices]
    const int tid = threadIdx.x;
    const int s   = blockIdx.x & 7;      // hidden slice 0..7
    const int grp = blockIdx.x >> 3;     // batch group 0..7 (batches grp*4..grp*4+3)
    const int r = tid >> 2;              // gate row 0..127 within slice
    const int q = tid & 3;               // k-quarter
    const int g = r >> 5, jr = r & 31;
    const int grow = g * 256 + s * 32 + jr;  // global gate row

    __shared__ __align__(16) float h_swz[4 * 256];   // [bi][c][q][e]
    __shared__ float gate_s[4][128];

    // ---- load Whh slice into registers, then pin with opaque asm ----
    float4 wreg[16];
    {
        const float4* wrow = (const float4*)(whh + (size_t)grow * 256 + q * 64);
#pragma unroll
        for (int c = 0; c < 16; ++c) wreg[c] = wrow[c];
    }
#pragma unroll
    for (int c = 0; c < 16; ++c)
        asm volatile("" : "+v"(wreg[c].x), "+v"(wreg[c].y),
                          "+v"(wreg[c].z), "+v"(wreg[c].w));

    // ---- carry c: tid<128 owns (bi=tid>>5, unit jj=tid&31) ----
    float cc = 0.f;
    if (tid < 128) {
        int bi = tid >> 5, jj = tid & 31;
        cc = hx[(size_t)B_ * LH_ + (grp * 4 + bi) * LH_ + s * 32 + jj];
    }

    for (int t = 1; t <= T_; ++t) {
        // ---- preload gx (independent of h) before the sync wait ----
        float gxv[4];
        if (q == 0) {
#pragma unroll
            for (int bi = 0; bi < 4; ++bi) {
                int nb = (t - 1) * B_ + grp * 4 + bi;
                gxv[bi] = gx[(size_t)nb * 1024 + grow];
            }
        }
        // ---- wait for previous step's h from the 8 slice-WGs of this group ----
        if (t > 1) {
            if (tid < 8) {
                while (__hip_atomic_load(&flags[grp * 8 + tid], __ATOMIC_ACQUIRE,
                                         __HIP_MEMORY_SCOPE_AGENT) < t - 1)
                    __builtin_amdgcn_s_sleep(1);
            }
            __syncthreads();
        }
        // ---- stage h for 4 batches into swizzled LDS ----
#pragma unroll
        for (int l = 0; l < 2; ++l) {
            int idx = tid + l * 512;                 // 0..1023
            int bi = idx >> 8, j = idx & 255;
            int b = grp * 4 + bi;
            int nb = (t - 1) * B_ + b;
            float hv;
            if (t == 1) hv = hx[b * LH_ + j];
            else        hv = __hip_atomic_load(&hbuf[((t - 1) & 1) * B_ * LH_ + b * LH_ + j],
                                               __ATOMIC_RELAXED, __HIP_MEMORY_SCOPE_AGENT);
            if (dones[nb]) hv = 0.f;
            int qq = j >> 6, ccc = (j >> 2) & 15, ee = j & 3;
            h_swz[bi * 256 + ccc * 16 + qq * 4 + ee] = hv;
        }
        __syncthreads();

        // ---- matvec: 128 rows x 4 batches, 4 threads/row over k ----
        float acc[4] = {0.f, 0.f, 0.f, 0.f};
#pragma unroll
        for (int c = 0; c < 16; ++c) {
            float4 w4 = wreg[c];
#pragma unroll
            for (int bi = 0; bi < 4; ++bi) {
                float4 h4 = *(const float4*)&h_swz[bi * 256 + c * 16 + q * 4];
                acc[bi] = fmaf(w4.x, h4.x, acc[bi]);
                acc[bi] = fmaf(w4.y, h4.y, acc[bi]);
                acc[bi] = fmaf(w4.z, h4.z, acc[bi]);
                acc[bi] = fmaf(w4.w, h4.w, acc[bi]);
            }
        }
#pragma unroll
        for (int bi = 0; bi < 4; ++bi) {
            acc[bi] += __shfl_xor(acc[bi], 1);
            acc[bi] += __shfl_xor(acc[bi], 2);
        }
        if (q == 0) {
#pragma unroll
            for (int bi = 0; bi < 4; ++bi)
                gate_s[bi][r] = acc[bi] + gxv[bi];
        }
        __syncthreads();

        // ---- pointwise cell + publish (tid<128: 4 batches x 32 units) ----
        if (tid < 128) {
            int bi = tid >> 5, jj = tid & 31;
            int b = grp * 4 + bi;
            int nb = (t - 1) * B_ + b;
            float gi = gate_s[bi][jj],      gf = gate_s[bi][32 + jj];
            float gg = gate_s[bi][64 + jj], go = gate_s[bi][96 + jj];
            float ccv = dones[nb] ? 0.f : cc;
            float si = 1.f / (1.f + expf(-gi));
            float sf = 1.f / (1.f + expf(-gf));
            float so = 1.f / (1.f + expf(-go));
            float c2 = sf * ccv + si * tanhf(gg);
            float h2 = so * tanhf(c2);
            cc = c2;
            int hidx = s * 32 + jj;
            hs[(size_t)nb * LH_ + hidx] = h2;
            __hip_atomic_store(&hbuf[(t & 1) * B_ * LH_ + b * LH_ + hidx], h2,
                               __ATOMIC_RELAXED, __HIP_MEMORY_SCOPE_AGENT);
        }
        __syncthreads();   // emits vmcnt(0): all waves' h stores drained before flag
        if (tid == 0)
            __hip_atomic_store(&flags[grp * 8 + s], t, __ATOMIC_RELEASE,
                               __HIP_MEMORY_SCOPE_AGENT);
    }
}

// ---------- heads: logits[N,16] + NaN guard, values[N] ----------
__global__ void head_k(const float* __restrict__ hs,
                       const float* __restrict__ aw, const float* __restrict__ ab,
                       const float* __restrict__ cw, const float* __restrict__ cb,
                       float* __restrict__ out) {
    int gid = blockIdx.x * 256 + threadIdx.x;       // N_*17
    if (gid >= N_ * 17) return;
    int n = gid / 17, r = gid % 17;
    const float* f = hs + (size_t)n * 256;
    if (r < 16) {
        const float* w = aw + r * 256;
        float acc = ab[r];
        for (int k = 0; k < 256; ++k) acc = fmaf(f[k], w[k], acc);
        if (isnan(acc)) acc = 1e-12f;
        out[(size_t)n * 16 + r] = acc;
    } else {
        float acc = cb[0];
        for (int k = 0; k < 256; ++k) acc = fmaf(f[k], cw[k], acc);
        out[(size_t)N_ * 16 + n] = acc;
    }
}

extern "C" void kernel_launch(void* const* d_in, const int* in_sizes, int n_in,
                              void* d_out, int out_size, void* d_ws, size_t ws_size,
                              hipStream_t stream) {
    const float* x      = (const float*)d_in[0];
    const int* la       = (const int*)d_in[1];
    const float* reward = (const float*)d_in[2];
    const unsigned char* dones = (const unsigned char*)d_in[3];
    const float* hx     = (const float*)d_in[4];
    const float* c1w = (const float*)d_in[5];  const float* c1b = (const float*)d_in[6];
    const float* c2w = (const float*)d_in[7];  const float* c2b = (const float*)d_in[8];
    const float* c3w = (const float*)d_in[9];  const float* c3b = (const float*)d_in[10];
    const float* fcw = (const float*)d_in[11]; const float* fcb = (const float*)d_in[12];
    const float* wih = (const float*)d_in[13]; const float* whh = (const float*)d_in[14];
    const float* bih = (const float*)d_in[15]; const float* bhh = (const float*)d_in[16];
    const float* aw  = (const float*)d_in[17]; const float* ab  = (const float*)d_in[18];
    const float* cw  = (const float*)d_in[19]; const float* cb  = (const float*)d_in[20];

    float* ws = (float*)d_ws;
    // region A (reused): h1 [N,32,20,20] then h3/hfc/gx
    float* h1  = ws;                          // 32,768,000 f
    float* h3  = ws;                          //  8,028,160 f
    float* hfc = ws + 8028160;                //  1,310,720 f
    float* gx  = ws + 9338880;                //  2,621,440 f
    // region B (reused): h2 [N,64,9,9] then hs
    float* h2  = ws + 32768000;               // 13,271,040 f
    float* hs  = ws + 32768000;               //    655,360 f
    // region C: persistent small buffers
    float* hbuf = ws + 46039040;              //    16,384 f
    int*   flags = (int*)(ws + 46055424);     //       256 i
    float* wT1  = ws + 46055680;              //     8,192 f
    float* wT2  = wT1 + 8192;                 //    32,768 f
    float* wT3  = wT2 + 32768;                //    36,864 f

    transpose_k<<<32, 256, 0, stream>>>(c1w, wT1, 32, 256);
    transpose_k<<<128, 256, 0, stream>>>(c2w, wT2, 64, 512);
    transpose_k<<<144, 256, 0, stream>>>(c3w, wT3, 64, 576);
    zero_flags_k<<<1, 256, 0, stream>>>(flags);

    conv1_k<<<4000, 256, 0, stream>>>(x, wT1, c1b, h1);
    conv2_k<<<810, 256, 0, stream>>>(h1, wT2, c2b, h2);
    conv3_k<<<490, 256, 0, stream>>>(h2, wT3, c3b, h3);

    gemm_tn<1><<<dim3(8, 40), 256, 0, stream>>>(h3, 3136, fcw, 3136, fcb, hfc, 512, 3136);
    gemm_tn<0><<<dim3(16, 40), 256, 0, stream>>>(hfc, 512, wih, 529, nullptr, gx, 1024, 512);
    gx_epi_k<<<10240, 256, 0, stream>>>(gx, reward, la, wih, bih, bhh);

    lstm64_k<<<64, 512, 0, stream>>>(gx, whh, dones, hx, hs, hbuf, flags);
    head_k<<<170, 256, 0, stream>>>(hs, aw, ab, cw, cb, (float*)d_out);
}

// Round 4
// 749.834 us; speedup vs baseline: 2.3164x; 1.9946x over previous
//
#include <hip/hip_runtime.h>
#include <math.h>

#define T_ 80
#define B_ 32
#define N_ 2560            // T_*B_
#define LH_ 256

typedef __attribute__((ext_vector_type(8))) short short8;
typedef __attribute__((ext_vector_type(4))) float f32x4;
#define MFMA16(a, b, c) __builtin_amdgcn_mfma_f32_16x16x32_bf16((a), (b), (c), 0, 0, 0)

__device__ __forceinline__ float lrelu(float v) { return v > 0.f ? v : 0.01f * v; }
__device__ __forceinline__ short f2bf(float f) {        // RNE float->bf16 bits
    unsigned u = __float_as_uint(f);
    return (short)((u + 0x7fffu + ((u >> 16) & 1u)) >> 16);
}

// ================= weight pack kernels (fp32 -> bf16, MFMA-friendly) =============
__global__ void pack1_k(const float* __restrict__ w, short* __restrict__ d) {
    int g = blockIdx.x * 256 + threadIdx.x;          // 8*32*32
    int ky = g >> 10, oc = (g >> 5) & 31, k = g & 31, kx = k >> 2, ci = k & 3;
    d[g] = f2bf(w[((oc * 4 + ci) * 8 + ky) * 8 + kx]);
}
__global__ void pack2_k(const float* __restrict__ w, short* __restrict__ d) {
    int g = blockIdx.x * 256 + threadIdx.x;          // 16*64*32
    int t = g >> 11, oc = (g >> 5) & 63, ci = g & 31, ky = t >> 2, kx = t & 3;
    d[g] = f2bf(w[((oc * 32 + ci) * 4 + ky) * 4 + kx]);
}
__global__ void pack3_k(const float* __restrict__ w, short* __restrict__ d) {
    int g = blockIdx.x * 256 + threadIdx.x;          // 18*64*32
    int tkc = g >> 11, oc = (g >> 5) & 63, c32 = g & 31;
    int t = tkc >> 1, kc = tkc & 1, ky = t / 3, kx = t % 3;
    d[g] = f2bf(w[((oc * 64 + kc * 32 + c32) * 3 + ky) * 3 + kx]);
}
__global__ void packfc_k(const float* __restrict__ w, short* __restrict__ d) {
    int g = blockIdx.x * 256 + threadIdx.x;          // 512*3136
    int j = g / 3136, kp = g % 3136, p = kp >> 6, oc = kp & 63;
    d[g] = f2bf(w[j * 3136 + oc * 49 + p]);
}
__global__ void packih_k(const float* __restrict__ w, short* __restrict__ d) {
    int g = blockIdx.x * 256 + threadIdx.x;          // 1024*512
    int r = g >> 9, k = g & 511;
    d[g] = f2bf(w[r * 529 + k]);
}
__global__ void zero_flags_k(int* __restrict__ flags) { flags[threadIdx.x] = 0; }

// ================= conv1 MFMA: x[N,4,84,84] -> h1_cl[N,400,32] bf16 ==============
// Half-image blocks (oy rows h*10..h*10+9). A-term k = kx*4+ci from channels-last
// LDS stage xs[ry][slot(x+1)][ci]; 8 ky terms of K=32.
#define C1_RS 344            // 86 x-slots * 4 ci (entries per row)
__global__ __launch_bounds__(512) void conv1_mfma(
    const float* __restrict__ x, const short* __restrict__ wp1,  // [8][32][32]
    const float* __restrict__ bias, short* __restrict__ h1) {    // [N][400][32]
    __shared__ short xs[44 * C1_RS];      // 30.3 KB
    __shared__ short ob[208 * 32];        // 13.3 KB
    int blk = blockIdx.x, n = blk >> 1, h = blk & 1, tid = threadIdx.x;
    // ---- stage 44 rows (iy = h*40-1 .. h*40+42) as bf16 channels-last ----
    for (int i = tid; i < 44 * 84; i += 512) {   // one float4 (4 x-values) each
        int ry = i / 84, xi4 = i % 84;           // xi4: which float4 in row? 84/4=21
        int ci = xi4 / 21, x4 = xi4 % 21;
        int iy = ry + h * 40 - 1;
        if (iy < 0 || iy > 83) continue;
        float4 v = *(const float4*)(x + (size_t)(n * 4 + ci) * 7056 + iy * 84 + x4 * 4);
        int base = ry * C1_RS + (x4 * 4 + 1) * 4 + ci;
        xs[base] = f2bf(v.x); xs[base + 4] = f2bf(v.y);
        xs[base + 8] = f2bf(v.z); xs[base + 12] = f2bf(v.w);
    }
    for (int i = tid; i < 44 * 4; i += 512)      // zero x-slot 0 (x = -1)
        xs[(i >> 2) * C1_RS + (i & 3)] = 0;
    if (h == 0) for (int i = tid; i < C1_RS; i += 512) xs[i] = 0;  // row iy=-1
    __syncthreads();

    int lane = tid & 63, wid = tid >> 6;
    int lr = lane & 15, kq = lane >> 4;
    // ---- hoist B-frags: 8 ky x 2 ntiles from global ----
    short8 bfr[8][2];
#pragma unroll
    for (int ky = 0; ky < 8; ++ky)
#pragma unroll
        for (int nt = 0; nt < 2; ++nt)
            bfr[ky][nt] = *(const short8*)&wp1[((ky * 32) + nt * 16 + lr) * 32 + kq * 8];
    float b0 = bias[lr], b1 = bias[16 + lr];

    for (int t = wid; t < 13; t += 8) {
        int p = t * 16 + lr; if (p > 199) p = 199;       // clamp (masked at store)
        int oy = p / 20, ox = p % 20;                    // local oy 0..9
        f32x4 acc0 = {0.f, 0.f, 0.f, 0.f}, acc1 = {0.f, 0.f, 0.f, 0.f};
#pragma unroll
        for (int ky = 0; ky < 8; ++ky) {
            int ry = oy * 4 + ky;                        // iy - (h*40-1)
            short8 af = *(const short8*)&xs[ry * C1_RS + ox * 16 + kq * 8];
            acc0 = MFMA16(af, bfr[ky][0], acc0);
            acc1 = MFMA16(af, bfr[ky][1], acc1);
        }
        int pm = t * 16 + kq * 4;
#pragma unroll
        for (int r = 0; r < 4; ++r) {
            ob[(pm + r) * 32 + lr]      = f2bf(lrelu(acc0[r] + b0));
            ob[(pm + r) * 32 + 16 + lr] = f2bf(lrelu(acc1[r] + b1));
        }
    }
    __syncthreads();
    uint4* dst = (uint4*)(h1 + (size_t)n * 12800 + h * 6400);
    for (int i = tid; i < 800; i += 512) dst[i] = ((uint4*)ob)[i];
}

// ================= conv2 MFMA: h1_cl -> h2_cl[N,81,64] bf16 ======================
__global__ __launch_bounds__(512) void conv2_mfma(
    const short* __restrict__ h1, const short* __restrict__ wp2,  // [16][64][32]
    const float* __restrict__ bias, short* __restrict__ h2) {
    __shared__ short in_s[400 * 40];      // 32 KB (pix stride padded 32->40)
    __shared__ short ob[96 * 64];         // 12.3 KB
    int n = blockIdx.x, tid = threadIdx.x;
    const uint4* src = (const uint4*)(h1 + (size_t)n * 12800);
    for (int i = tid; i < 1600; i += 512) {           // pix = i>>2, chunk = i&3
        *(uint4*)&in_s[(i >> 2) * 40 + (i & 3) * 8] = src[i];
    }
    __syncthreads();
    int lane = tid & 63, wid = tid >> 6;
    int nt = wid & 3, mh = wid >> 2;
    int lr = lane & 15, kq = lane >> 4;
    short8 bfr[16];
#pragma unroll
    for (int t = 0; t < 16; ++t)
        bfr[t] = *(const short8*)&wp2[(t * 64 + nt * 16 + lr) * 32 + kq * 8];
    float bl = bias[nt * 16 + lr];
    for (int mt = mh * 3; mt < mh * 3 + 3; ++mt) {
        int p = mt * 16 + lr; if (p > 80) p = 80;
        int oy = p / 9, ox = p % 9;
        f32x4 acc = {0.f, 0.f, 0.f, 0.f};
#pragma unroll
        for (int ky = 0; ky < 4; ++ky)
#pragma unroll
            for (int kx = 0; kx < 4; ++kx) {
                int pix = (oy * 2 + ky) * 20 + ox * 2 + kx;
                short8 af = *(const short8*)&in_s[pix * 40 + kq * 8];
                acc = MFMA16(af, bfr[ky * 4 + kx], acc);
            }
        int pm = mt * 16 + kq * 4;
#pragma unroll
        for (int r = 0; r < 4; ++r)
            ob[(pm + r) * 64 + nt * 16 + lr] = f2bf(lrelu(acc[r] + bl));
    }
    __syncthreads();
    uint4* dst = (uint4*)(h2 + (size_t)n * 5184);
    for (int i = tid; i < 648; i += 512) dst[i] = ((uint4*)ob)[i];
}

// ================= conv3 MFMA: h2_cl -> h3_cl[N,49*64] bf16 ======================
__global__ __launch_bounds__(512) void conv3_mfma(
    const short* __restrict__ h2, const short* __restrict__ wp3,  // [9][2][64][32]
    const float* __restrict__ bias, short* __restrict__ h3) {
    __shared__ short in_s[81 * 72];       // 11.7 KB (pix stride 64->72)
    __shared__ short ob[64 * 64];         // 8 KB
    int n = blockIdx.x, tid = threadIdx.x;
    const uint4* src = (const uint4*)(h2 + (size_t)n * 5184);
    for (int i = tid; i < 648; i += 512) {            // pix = i>>3, chunk = i&7
        *(uint4*)&in_s[(i >> 3) * 72 + (i & 7) * 8] = src[i];
    }
    __syncthreads();
    int lane = tid & 63, wid = tid >> 6;
    int nt = wid & 3, mh = wid >> 2;
    int lr = lane & 15, kq = lane >> 4;
    short8 bfr[18];
#pragma unroll
    for (int t = 0; t < 18; ++t)
        bfr[t] = *(const short8*)&wp3[(t * 64 + nt * 16 + lr) * 32 + kq * 8];
    float bl = bias[nt * 16 + lr];
    for (int mt = mh * 2; mt < mh * 2 + 2; ++mt) {
        int p = mt * 16 + lr; if (p > 48) p = 48;
        int oy = p / 7, ox = p % 7;
        f32x4 acc = {0.f, 0.f, 0.f, 0.f};
#pragma unroll
        for (int ky = 0; ky < 3; ++ky)
#pragma unroll
            for (int kx = 0; kx < 3; ++kx) {
                int pix = (oy + ky) * 9 + ox + kx;
#pragma unroll
                for (int kc = 0; kc < 2; ++kc) {
                    short8 af = *(const short8*)&in_s[pix * 72 + kc * 32 + kq * 8];
                    acc = MFMA16(af, bfr[(ky * 3 + kx) * 2 + kc], acc);
                }
            }
        int pm = mt * 16 + kq * 4;
#pragma unroll
        for (int r = 0; r < 4; ++r)
            ob[(pm + r) * 64 + nt * 16 + lr] = f2bf(lrelu(acc[r] + bl));
    }
    __syncthreads();
    uint4* dst = (uint4*)(h3 + (size_t)n * 3136);
    for (int i = tid; i < 392; i += 512) dst[i] = ((uint4*)ob)[i];
}

// ========== bf16 GEMM, tile 128x128: C[M,N] = A[M,K] @ B[N,K]^T =================
// OUT=1: +bias, lrelu, bf16 out (via LDS bounce).  OUT=0: raw fp32 out.
template <int OUT>
__global__ __launch_bounds__(256) void gemm_bf16(
    const short* __restrict__ A, const short* __restrict__ B,
    const float* __restrict__ bias, void* __restrict__ Cout,
    int M, int N, int K, int ldc) {
    __shared__ short smem[20480];                    // As[2][5120] | Bs[2][5120]
    int m0 = blockIdx.y * 128, n0 = blockIdx.x * 128;
    int tid = threadIdx.x;
    int lane = tid & 63, wid = tid >> 6;
    int wr = wid >> 1, wc = wid & 1;
    int lr = lane & 15, kq = lane >> 4;
    f32x4 acc[4][4];
#pragma unroll
    for (int i = 0; i < 4; ++i)
#pragma unroll
        for (int j = 0; j < 4; ++j) acc[i][j] = (f32x4){0.f, 0.f, 0.f, 0.f};

    int nsteps = K >> 5;
#define STAGE(k0, buf)                                                          \
    {                                                                           \
        short* As = smem + (buf) * 5120;                                        \
        short* Bs = smem + 10240 + (buf) * 5120;                                \
        for (int i = tid; i < 512; i += 256) {                                  \
            int row = i >> 2, c4 = i & 3;                                       \
            *(uint4*)&As[row * 40 + c4 * 8] =                                   \
                *(const uint4*)&A[(size_t)(m0 + row) * K + (k0) + c4 * 8];      \
            *(uint4*)&Bs[row * 40 + c4 * 8] =                                   \
                *(const uint4*)&B[(size_t)(n0 + row) * K + (k0) + c4 * 8];      \
        }                                                                       \
    }
    STAGE(0, 0);
    __syncthreads();
    for (int ks = 0; ks < nsteps; ++ks) {
        int buf = ks & 1;
        if (ks + 1 < nsteps) STAGE((ks + 1) * 32, buf ^ 1);
        short* As = smem + buf * 5120;
        short* Bs = smem + 10240 + buf * 5120;
        short8 af[4], bfr[4];
#pragma unroll
        for (int i = 0; i < 4; ++i)
            af[i] = *(const short8*)&As[(wr * 64 + i * 16 + lr) * 40 + kq * 8];
#pragma unroll
        for (int j = 0; j < 4; ++j)
            bfr[j] = *(const short8*)&Bs[(wc * 64 + j * 16 + lr) * 40 + kq * 8];
#pragma unroll
        for (int i = 0; i < 4; ++i)
#pragma unroll
            for (int j = 0; j < 4; ++j)
                acc[i][j] = MFMA16(af[i], bfr[j], acc[i][j]);
        __syncthreads();
    }
#undef STAGE
    if (OUT == 0) {
        float* C = (float*)Cout;
#pragma unroll
        for (int i = 0; i < 4; ++i)
#pragma unroll
            for (int j = 0; j < 4; ++j)
#pragma unroll
                for (int r = 0; r < 4; ++r) {
                    int row = m0 + wr * 64 + i * 16 + kq * 4 + r;
                    int col = n0 + wc * 64 + j * 16 + lr;
                    C[(size_t)row * ldc + col] = acc[i][j][r];
                }
    } else {
        short* ob = smem;                             // 128x128 bf16 bounce
#pragma unroll
        for (int i = 0; i < 4; ++i)
#pragma unroll
            for (int j = 0; j < 4; ++j) {
                int col = wc * 64 + j * 16 + lr;
                float bl = bias[n0 + col];
#pragma unroll
                for (int r = 0; r < 4; ++r) {
                    int row = wr * 64 + i * 16 + kq * 4 + r;
                    ob[row * 128 + col] = f2bf(lrelu(acc[i][j][r] + bl));
                }
            }
        __syncthreads();
        short* C = (short*)Cout;
        for (int i = tid; i < 2048; i += 256) {
            int row = i >> 4, c16 = i & 15;
            *(uint4*)&C[(size_t)(m0 + row) * ldc + n0 + c16 * 8] =
                *(uint4*)&ob[row * 128 + c16 * 8];
        }
    }
}

// ---------- gates epilogue: + bih + bhh + reward*wih[:,512] + wih[:,513+la] ------
__global__ void gx_epi_k(float* __restrict__ gx, const float* __restrict__ reward,
                         const int* __restrict__ la, const float* __restrict__ wih,
                         const float* __restrict__ bih, const float* __restrict__ bhh) {
    int gid = blockIdx.x * 256 + threadIdx.x;       // N_*1024
    int n = gid >> 10, j = gid & 1023;
    const float* wr = wih + (size_t)j * 529;
    gx[gid] += bih[j] + bhh[j] + reward[n] * wr[512] + wr[513 + la[n]];
}

// ---------- LSTM: 64 WGs = 8 hidden-slices x 8 batch-groups (4 batches each) -----
__global__ __launch_bounds__(512) void lstm64_k(
    const float* __restrict__ gx, const float* __restrict__ whh,
    const unsigned char* __restrict__ dones, const float* __restrict__ hx,
    float* __restrict__ hs, float* __restrict__ hbuf, int* __restrict__ flags) {
    const int tid = threadIdx.x;
    const int s   = blockIdx.x & 7;
    const int grp = blockIdx.x >> 3;
    const int r = tid >> 2;
    const int q = tid & 3;
    const int g = r >> 5, jr = r & 31;
    const int grow = g * 256 + s * 32 + jr;

    __shared__ __align__(16) float h_swz[4 * 256];
    __shared__ float gate_s[4][128];

    float4 wreg[16];
    {
        const float4* wrow = (const float4*)(whh + (size_t)grow * 256 + q * 64);
#pragma unroll
        for (int c = 0; c < 16; ++c) wreg[c] = wrow[c];
    }
#pragma unroll
    for (int c = 0; c < 16; ++c)
        asm volatile("" : "+v"(wreg[c].x), "+v"(wreg[c].y),
                          "+v"(wreg[c].z), "+v"(wreg[c].w));

    float cc = 0.f;
    if (tid < 128) {
        int bi = tid >> 5, jj = tid & 31;
        cc = hx[(size_t)B_ * LH_ + (grp * 4 + bi) * LH_ + s * 32 + jj];
    }

    for (int t = 1; t <= T_; ++t) {
        float gxv[4];
        if (q == 0) {
#pragma unroll
            for (int bi = 0; bi < 4; ++bi) {
                int nb = (t - 1) * B_ + grp * 4 + bi;
                gxv[bi] = gx[(size_t)nb * 1024 + grow];
            }
        }
        if (t > 1) {
            if (tid < 8) {
                while (__hip_atomic_load(&flags[grp * 8 + tid], __ATOMIC_ACQUIRE,
                                         __HIP_MEMORY_SCOPE_AGENT) < t - 1)
                    __builtin_amdgcn_s_sleep(1);
            }
            __syncthreads();
        }
#pragma unroll
        for (int l = 0; l < 2; ++l) {
            int idx = tid + l * 512;
            int bi = idx >> 8, j = idx & 255;
            int b = grp * 4 + bi;
            int nb = (t - 1) * B_ + b;
            float hv;
            if (t == 1) hv = hx[b * LH_ + j];
            else        hv = __hip_atomic_load(&hbuf[((t - 1) & 1) * B_ * LH_ + b * LH_ + j],
                                               __ATOMIC_RELAXED, __HIP_MEMORY_SCOPE_AGENT);
            if (dones[nb]) hv = 0.f;
            int qq = j >> 6, ccc = (j >> 2) & 15, ee = j & 3;
            h_swz[bi * 256 + ccc * 16 + qq * 4 + ee] = hv;
        }
        __syncthreads();

        float acc[4] = {0.f, 0.f, 0.f, 0.f};
#pragma unroll
        for (int c = 0; c < 16; ++c) {
            float4 w4 = wreg[c];
#pragma unroll
            for (int bi = 0; bi < 4; ++bi) {
                float4 h4 = *(const float4*)&h_swz[bi * 256 + c * 16 + q * 4];
                acc[bi] = fmaf(w4.x, h4.x, acc[bi]);
                acc[bi] = fmaf(w4.y, h4.y, acc[bi]);
                acc[bi] = fmaf(w4.z, h4.z, acc[bi]);
                acc[bi] = fmaf(w4.w, h4.w, acc[bi]);
            }
        }
#pragma unroll
        for (int bi = 0; bi < 4; ++bi) {
            acc[bi] += __shfl_xor(acc[bi], 1);
            acc[bi] += __shfl_xor(acc[bi], 2);
        }
        if (q == 0) {
#pragma unroll
            for (int bi = 0; bi < 4; ++bi)
                gate_s[bi][r] = acc[bi] + gxv[bi];
        }
        __syncthreads();

        if (tid < 128) {
            int bi = tid >> 5, jj = tid & 31;
            int b = grp * 4 + bi;
            int nb = (t - 1) * B_ + b;
            float gi = gate_s[bi][jj],      gf = gate_s[bi][32 + jj];
            float gg = gate_s[bi][64 + jj], go = gate_s[bi][96 + jj];
            float ccv = dones[nb] ? 0.f : cc;
            float si = 1.f / (1.f + expf(-gi));
            float sf = 1.f / (1.f + expf(-gf));
            float so = 1.f / (1.f + expf(-go));
            float c2 = sf * ccv + si * tanhf(gg);
            float h2 = so * tanhf(c2);
            cc = c2;
            int hidx = s * 32 + jj;
            hs[(size_t)nb * LH_ + hidx] = h2;
            __hip_atomic_store(&hbuf[(t & 1) * B_ * LH_ + b * LH_ + hidx], h2,
                               __ATOMIC_RELAXED, __HIP_MEMORY_SCOPE_AGENT);
        }
        __syncthreads();
        if (tid == 0)
            __hip_atomic_store(&flags[grp * 8 + s], t, __ATOMIC_RELEASE,
                               __HIP_MEMORY_SCOPE_AGENT);
    }
}

// ---------- heads ----------
__global__ void head_k(const float* __restrict__ hs,
                       const float* __restrict__ aw, const float* __restrict__ ab,
                       const float* __restrict__ cw, const float* __restrict__ cb,
                       float* __restrict__ out) {
    int gid = blockIdx.x * 256 + threadIdx.x;       // N_*17
    if (gid >= N_ * 17) return;
    int n = gid / 17, r = gid % 17;
    const float* f = hs + (size_t)n * 256;
    if (r < 16) {
        const float* w = aw + r * 256;
        float acc = ab[r];
        for (int k = 0; k < 256; ++k) acc = fmaf(f[k], w[k], acc);
        if (isnan(acc)) acc = 1e-12f;
        out[(size_t)n * 16 + r] = acc;
    } else {
        float acc = cb[0];
        for (int k = 0; k < 256; ++k) acc = fmaf(f[k], cw[k], acc);
        out[(size_t)N_ * 16 + n] = acc;
    }
}

extern "C" void kernel_launch(void* const* d_in, const int* in_sizes, int n_in,
                              void* d_out, int out_size, void* d_ws, size_t ws_size,
                              hipStream_t stream) {
    const float* x      = (const float*)d_in[0];
    const int* la       = (const int*)d_in[1];
    const float* reward = (const float*)d_in[2];
    const unsigned char* dones = (const unsigned char*)d_in[3];
    const float* hx     = (const float*)d_in[4];
    const float* c1w = (const float*)d_in[5];  const float* c1b = (const float*)d_in[6];
    const float* c2w = (const float*)d_in[7];  const float* c2b = (const float*)d_in[8];
    const float* c3w = (const float*)d_in[9];  const float* c3b = (const float*)d_in[10];
    const float* fcw = (const float*)d_in[11]; const float* fcb = (const float*)d_in[12];
    const float* wih = (const float*)d_in[13]; const float* whh = (const float*)d_in[14];
    const float* bih = (const float*)d_in[15]; const float* bhh = (const float*)d_in[16];
    const float* aw  = (const float*)d_in[17]; const float* ab  = (const float*)d_in[18];
    const float* cw  = (const float*)d_in[19]; const float* cb  = (const float*)d_in[20];

    char* wsb = (char*)d_ws;
    short* h1   = (short*)(wsb);                         // 65,536,000 B
    short* h2   = (short*)(wsb + 65536000);              // 26,542,080
    short* h3   = (short*)(wsb + 92078080);              // 16,056,320
    short* hfc  = (short*)(wsb + 108134400);             //  2,621,440
    float* gx   = (float*)(wsb + 110755840);             // 10,485,760
    float* hs   = (float*)(wsb + 121241600);             //  2,621,440
    float* hbuf = (float*)(wsb + 123863040);             //     65,536
    int*   flags= (int*)  (wsb + 123928576);             //      1,024
    short* wp1  = (short*)(wsb + 123929600);             //     16,384
    short* wp2  = (short*)(wsb + 123945984);             //     65,536
    short* wp3  = (short*)(wsb + 124011520);             //     73,728
    short* wfcP = (short*)(wsb + 124085248);             //  3,211,264
    short* wihP = (short*)(wsb + 127296512);             //  1,048,576

    pack1_k<<<32, 256, 0, stream>>>(c1w, wp1);
    pack2_k<<<128, 256, 0, stream>>>(c2w, wp2);
    pack3_k<<<144, 256, 0, stream>>>(c3w, wp3);
    packfc_k<<<6272, 256, 0, stream>>>(fcw, wfcP);
    packih_k<<<2048, 256, 0, stream>>>(wih, wihP);
    zero_flags_k<<<1, 256, 0, stream>>>(flags);

    conv1_mfma<<<5120, 512, 0, stream>>>(x, wp1, c1b, h1);
    conv2_mfma<<<2560, 512, 0, stream>>>(h1, wp2, c2b, h2);
    conv3_mfma<<<2560, 512, 0, stream>>>(h2, wp3, c3b, h3);

    gemm_bf16<1><<<dim3(4, 20), 256, 0, stream>>>(h3, wfcP, fcb, hfc, 2560, 512, 3136, 512);
    gemm_bf16<0><<<dim3(8, 20), 256, 0, stream>>>(hfc, wihP, nullptr, gx, 2560, 1024, 512, 1024);
    gx_epi_k<<<10240, 256, 0, stream>>>(gx, reward, la, wih, bih, bhh);

    lstm64_k<<<64, 512, 0, stream>>>(gx, whh, dones, hx, hs, hbuf, flags);
    head_k<<<170, 256, 0, stream>>>(hs, aw, ab, cw, cb, (float*)d_out);
}